// Round 12
// baseline (4142.864 us; speedup 1.0000x reference)
//
#include <hip/hip_runtime.h>
#include <hip/hip_fp16.h>

#define B_ 512
#define T_ 256
#define H_ 1024
#define G4_ 4096
#define KL_ 18   // k-slices (of 32) in LDS, consumed by kh=0 waves
#define KG_ 14   // k-slices from L2, consumed by kh=1 waves

typedef _Float16 half8 __attribute__((ext_vector_type(8)));
typedef float f32x4 __attribute__((ext_vector_type(4)));

__device__ __forceinline__ float fast_sigmoid(float x) {
    return 1.0f / (1.0f + __expf(-x));
}
__device__ __forceinline__ float fast_tanh(float x) {
    float x2 = fminf(fmaxf(2.0f * x, -30.0f), 30.0f);
    float e = __expf(x2);
    return (e - 1.0f) / (e + 1.0f);
}

// Repack W_hh [4096 x 1024] fp32 -> fp16 MFMA B-fragment order, split into
// W_lds (ki 0..17, per slot 73728 halves = 144 KB, read once at startup) and
// W_l2 (ki 18..31, per j-block 28672 halves = 56 KB; hot set 3.5 MB/XCD).
__global__ void pack_w(const float* __restrict__ Whh,
                       _Float16* __restrict__ Wlds, _Float16* __restrict__ Wl2) {
    int idx = blockIdx.x * blockDim.x + threadIdx.x;   // over 4096*1024
    int gc = idx >> 10, k = idx & 1023;
    int nt = gc >> 10, u = gc & 1023;
    int jb = u >> 4, lk = u & 15;
    int ki = k >> 5, hi = (k >> 3) & 3, e = k & 7;
    int l = hi * 16 + lk;
    _Float16 v = (_Float16)Whh[idx];
    int frag = nt * 512 + l * 8 + e;
    if (ki < KL_) {
        int slot = jb >> 1, wj = jb & 1;
        Wlds[(size_t)slot * 73728 + wj * 36864 + ki * 2048 + frag] = v;
    } else {
        Wl2[(size_t)jb * 28672 + (ki - KL_) * 2048 + frag] = v;
    }
}

__global__ void init_misc(const float* __restrict__ bih, const float* __restrict__ bhh,
                          const float* __restrict__ bout,
                          float* __restrict__ bias, float* __restrict__ out) {
    int idx = blockIdx.x * blockDim.x + threadIdx.x;   // 131072 threads
    if (idx < G4_) bias[idx] = bih[idx] + bhh[idx];
    if (idx < B_ * T_) out[idx] = bout[0];
}

// Persistent kernel, PLAIN launch (r11-proven startup spin barrier). 256 WGs x
// 512 thr, 1 WG/CU (160 KB LDS). 8 waves = 2 row x 2 col x 2 k-half:
//   kh=0: k 0..17, B from LDS; also owns bias/x init, elementwise, h-store, out.
//   kh=1: k 18..31, B from L2; writes partial acc to a 16 KB LDS exchange.
// Wave->SIMD: w%4, so each SIMD gets one kh0 (LDS-bound) + one kh1 (L2-bound)
// wave -> complementary co-scheduling. L2/step/CU: A 256 + B 224 = 480 KB
// (vs 640 in the 4x2 grid). c in VGPRs; h double-buffered; split arrive/wait
// XCD barrier + L1 invalidate.
__global__ __launch_bounds__(512, 1)
void lstm_persist(const _Float16* __restrict__ Wlds,
                  const _Float16* __restrict__ Wl2,
                  const float* __restrict__ bias,
                  const float* __restrict__ x,
                  const float* __restrict__ Wih,
                  const float* __restrict__ Wout,
                  _Float16* __restrict__ hbuf,        // [8 xcd][2 phase][65536 halves]
                  float* __restrict__ out,
                  unsigned int* __restrict__ cnts) {  // [xcd] slot ctr, [8] startup,
                                                      // [16+xcd*32] barrier, [512+blk] slotmap
    extern __shared__ _Float16 Wl[];   // 73728 halves W + 16 KB reduce = 160 KB

    const int tid = threadIdx.x;
    unsigned int xcc;
    asm volatile("s_getreg_b32 %0, hwreg(HW_REG_XCC_ID)" : "=s"(xcc));
    const int xcd = (int)(xcc & 7u);
    if (tid == 0) {
        unsigned int s = __hip_atomic_fetch_add(&cnts[xcd], 1u,
                                                __ATOMIC_RELAXED, __HIP_MEMORY_SCOPE_AGENT);
        __hip_atomic_store(&cnts[512 + blockIdx.x], s,
                           __ATOMIC_RELAXED, __HIP_MEMORY_SCOPE_AGENT);
        __hip_atomic_fetch_add(&cnts[8], 1u, __ATOMIC_ACQ_REL, __HIP_MEMORY_SCOPE_AGENT);
        while (__hip_atomic_load(&cnts[8], __ATOMIC_ACQUIRE, __HIP_MEMORY_SCOPE_AGENT) < 256u)
            __builtin_amdgcn_s_sleep(2);
    }
    __syncthreads();
    const int slot = (int)__hip_atomic_load(&cnts[512 + blockIdx.x],
                                            __ATOMIC_RELAXED, __HIP_MEMORY_SCOPE_AGENT);
    const int nactive = (int)min(32u, __hip_atomic_load(&cnts[xcd], __ATOMIC_RELAXED,
                                                        __HIP_MEMORY_SCOPE_AGENT));
    if (slot >= 32) return;   // insurance only

    const int w = tid >> 6, l = tid & 63;
    const int lk = l & 15, hi = l >> 4;
    const int kh = w >> 2;                    // k-half (0: LDS, 1: L2)
    const int wj = (w >> 1) & 1, wr = w & 1;  // col-wave, row-wave
    const int pr = w & 3;                     // pair id (shared by w and w+4)
    const int row0 = wr * 32;
    const int u = slot * 32 + wj * 16 + lk;

    // one-time: this slot's W ki 0..17 -> LDS (9216 half8, 512 threads x 18)
    {
        const half8* src = (const half8*)(Wlds + (size_t)slot * 73728);
        half8* dst = (half8*)Wl;
#pragma unroll
        for (int o = 0; o < 18; ++o) dst[tid + o * 512] = src[tid + o * 512];
    }
    // per-thread constants (kh0 only does init/elementwise)
    float bz[4], wi4[4];
    float wout = 0.f;
    if (kh == 0) {
#pragma unroll
        for (int nt = 0; nt < 4; ++nt) {
            int gc = nt * 1024 + u;
            bz[nt] = bias[gc];
            wi4[nt] = Wih[gc];
        }
        wout = Wout[u];
    }
    int rowsl[8], rowsg[8];                   // [sub*4 + r]
#pragma unroll
    for (int s = 0; s < 2; ++s)
#pragma unroll
    for (int r = 0; r < 4; ++r) {
        rowsl[s * 4 + r] = row0 + s * 16 + hi * 4 + r;
        rowsg[s * 4 + r] = xcd * 64 + rowsl[s * 4 + r];
    }
    const int kb = u >> 3, ue = u & 7;
    f32x4 creg[2] = {{0.f, 0.f, 0.f, 0.f}, {0.f, 0.f, 0.f, 0.f}};
    __syncthreads();

    _Float16* hx = hbuf + (size_t)xcd * 2 * 65536;
    const _Float16* Bg = Wl2 + ((size_t)slot * 2 + wj) * 28672 + l * 8;
    f32x4* red4 = (f32x4*)((char*)Wl + 147456);   // [pr][nt][lane] f32x4, 16 KB
    unsigned int* barp = &cnts[16 + xcd * 32];

    float xv[8];
    if (kh == 0) {
#pragma unroll
        for (int i = 0; i < 8; ++i) xv[i] = x[rowsg[i] * T_];
    }

    for (int t = 0; t < T_; ++t) {
        // -------- wait phase (h(t-1) from all slots visible) --------
        if (t > 0) {
            if (tid == 0) {
                unsigned int tgt = (unsigned int)nactive * (unsigned int)t;
                while (__hip_atomic_load(barp, __ATOMIC_RELAXED, __HIP_MEMORY_SCOPE_AGENT) < tgt)
                    __builtin_amdgcn_s_sleep(2);
            }
            __syncthreads();
            asm volatile("buffer_inv sc0" ::: "memory");   // drop stale L1 lines
        }

        const int wb = t & 1, rb = wb ^ 1;
        f32x4 acc[2][4];
        if (kh == 0) {
#pragma unroll
            for (int s = 0; s < 2; ++s)
#pragma unroll
            for (int nt = 0; nt < 4; ++nt)
#pragma unroll
            for (int r = 0; r < 4; ++r)
                acc[s][nt][r] = bz[nt] + xv[s * 4 + r] * wi4[nt];
        } else {
#pragma unroll
            for (int s = 0; s < 2; ++s)
#pragma unroll
            for (int nt = 0; nt < 4; ++nt)
                acc[s][nt] = (f32x4){0.f, 0.f, 0.f, 0.f};
        }

        if (t > 0) {
            const _Float16* Ap0 = hx + rb * 65536 + hi * 512 + (row0 + lk) * 8;
            const _Float16* Ap1 = Ap0 + 128;   // +16 rows
            if (kh == 0) {
                // k-slices 0..17, B from LDS
#pragma unroll 6
                for (int ki = 0; ki < KL_; ++ki) {
                    half8 a0 = *(const half8*)(Ap0 + ki * 2048);
                    half8 a1 = *(const half8*)(Ap1 + ki * 2048);
                    const _Float16* bp = Wl + wj * 36864 + ki * 2048 + l * 8;
#pragma unroll
                    for (int nt = 0; nt < 4; ++nt) {
                        half8 b = *(const half8*)(bp + nt * 512);
                        acc[0][nt] = __builtin_amdgcn_mfma_f32_16x16x32_f16(a0, b, acc[0][nt], 0, 0, 0);
                        acc[1][nt] = __builtin_amdgcn_mfma_f32_16x16x32_f16(a1, b, acc[1][nt], 0, 0, 0);
                    }
                }
            } else {
                // k-slices 18..31, B from L2 in bursts of 4 (then 2)
                half8 bb[16];
#pragma unroll
                for (int b0 = 0; b0 < 12; b0 += 4) {
#pragma unroll
                    for (int q = 0; q < 16; ++q)
                        bb[q] = *(const half8*)(Bg + (b0 + (q >> 2)) * 2048 + (q & 3) * 512);
#pragma unroll
                    for (int kg = 0; kg < 4; ++kg) {
                        half8 a0 = *(const half8*)(Ap0 + (KL_ + b0 + kg) * 2048);
                        half8 a1 = *(const half8*)(Ap1 + (KL_ + b0 + kg) * 2048);
#pragma unroll
                        for (int nt = 0; nt < 4; ++nt) {
                            acc[0][nt] = __builtin_amdgcn_mfma_f32_16x16x32_f16(a0, bb[kg * 4 + nt], acc[0][nt], 0, 0, 0);
                            acc[1][nt] = __builtin_amdgcn_mfma_f32_16x16x32_f16(a1, bb[kg * 4 + nt], acc[1][nt], 0, 0, 0);
                        }
                    }
                }
#pragma unroll
                for (int q = 0; q < 8; ++q)
                    bb[q] = *(const half8*)(Bg + (12 + (q >> 2)) * 2048 + (q & 3) * 512);
#pragma unroll
                for (int kg = 0; kg < 2; ++kg) {
                    half8 a0 = *(const half8*)(Ap0 + (KL_ + 12 + kg) * 2048);
                    half8 a1 = *(const half8*)(Ap1 + (KL_ + 12 + kg) * 2048);
#pragma unroll
                    for (int nt = 0; nt < 4; ++nt) {
                        acc[0][nt] = __builtin_amdgcn_mfma_f32_16x16x32_f16(a0, bb[kg * 4 + nt], acc[0][nt], 0, 0, 0);
                        acc[1][nt] = __builtin_amdgcn_mfma_f32_16x16x32_f16(a1, bb[kg * 4 + nt], acc[1][nt], 0, 0, 0);
                    }
                }
            }
        }

        // -------- k-half exchange (LDS, f32) + elementwise --------
        _Float16* hn = hx + wb * 65536;
        float p8[8];
        if (kh == 1) {
#pragma unroll
            for (int nt = 0; nt < 4; ++nt) red4[(pr * 4 + nt) * 64 + l] = acc[0][nt];
        }
        __syncthreads();
        if (kh == 0) {
#pragma unroll
            for (int nt = 0; nt < 4; ++nt) acc[0][nt] += red4[(pr * 4 + nt) * 64 + l];
        }
        __syncthreads();
        if (kh == 1) {
#pragma unroll
            for (int nt = 0; nt < 4; ++nt) red4[(pr * 4 + nt) * 64 + l] = acc[1][nt];
        } else {
            // elementwise for sub-tile 0 while kh1 writes its second half
#pragma unroll
            for (int r = 0; r < 4; ++r) {
                float iv = fast_sigmoid(acc[0][0][r]);
                float fv = fast_sigmoid(acc[0][1][r]);
                float gv = fast_tanh(acc[0][2][r]);
                float ov = fast_sigmoid(acc[0][3][r]);
                float cv = fv * creg[0][r] + iv * gv;
                creg[0][r] = cv;
                float hv = ov * fast_tanh(cv);
                hn[(kb * 64 + rowsl[r]) * 8 + ue] = (_Float16)hv;
                p8[r] = hv * wout;
            }
        }
        __syncthreads();
        if (kh == 0) {
#pragma unroll
            for (int nt = 0; nt < 4; ++nt) acc[1][nt] += red4[(pr * 4 + nt) * 64 + l];
#pragma unroll
            for (int r = 0; r < 4; ++r) {
                float iv = fast_sigmoid(acc[1][0][r]);
                float fv = fast_sigmoid(acc[1][1][r]);
                float gv = fast_tanh(acc[1][2][r]);
                float ov = fast_sigmoid(acc[1][3][r]);
                float cv = fv * creg[1][r] + iv * gv;
                creg[1][r] = cv;
                float hv = ov * fast_tanh(cv);
                hn[(kb * 64 + rowsl[4 + r]) * 8 + ue] = (_Float16)hv;
                p8[4 + r] = hv * wout;
            }
        }

        // -------- arrive phase: h stores drained by syncthreads, then signal --------
        if (t < T_ - 1) {
            __syncthreads();   // per-wave s_waitcnt vmcnt(0) drains h stores first
            if (tid == 0)
                __hip_atomic_fetch_add(barp, 1u, __ATOMIC_RELAXED, __HIP_MEMORY_SCOPE_AGENT);
        }

        // barrier-latency hiding: out projection + x prefetch (kh0 only)
        if (kh == 0) {
#pragma unroll
            for (int m = 1; m <= 8; m <<= 1) {
#pragma unroll
                for (int i = 0; i < 8; ++i) p8[i] += __shfl_xor(p8[i], m);
            }
            if (lk == 0) {
#pragma unroll
                for (int i = 0; i < 8; ++i)
                    atomicAdd(&out[rowsg[i] * T_ + t], p8[i]);
            }
            if (t < T_ - 1) {
#pragma unroll
                for (int i = 0; i < 8; ++i) xv[i] = x[rowsg[i] * T_ + t + 1];
            }
        }
    }
}

extern "C" void kernel_launch(void* const* d_in, const int* in_sizes, int n_in,
                              void* d_out, int out_size, void* d_ws, size_t ws_size,
                              hipStream_t stream) {
    const float* x    = (const float*)d_in[0];
    const float* Wih  = (const float*)d_in[1];
    const float* Whh  = (const float*)d_in[2];
    const float* bih  = (const float*)d_in[3];
    const float* bhh  = (const float*)d_in[4];
    const float* Wout = (const float*)d_in[5];
    const float* bout = (const float*)d_in[6];
    float* out = (float*)d_out;

    char* ws = (char*)d_ws;
    _Float16* Wlds = (_Float16*)ws;                        // 4.5 MB (32 x 144 KB)
    _Float16* Wl2  = (_Float16*)(ws + 4718592);            // 3.5 MB (64 x 56 KB)
    _Float16* hbuf = (_Float16*)(ws + (8 << 20));          // 2 MB (8 xcd x 2 x 128 KB)
    float* bias    = (float*)(ws + (10 << 20));            // 16 KB
    unsigned int* cnts = (unsigned int*)(ws + (10 << 20) + (64 << 10));  // 4 KB

    hipMemsetAsync(cnts, 0, 4096, stream);
    pack_w<<<(G4_ * H_) / 256, 256, 0, stream>>>(Whh, Wlds, Wl2);
    init_misc<<<512, 256, 0, stream>>>(bih, bhh, bout, bias, out);

    (void)hipFuncSetAttribute((const void*)lstm_persist,
                              hipFuncAttributeMaxDynamicSharedMemorySize, 163840);
    lstm_persist<<<dim3(256), dim3(512), 163840, stream>>>(
        Wlds, Wl2, bias, x, Wih, Wout, hbuf, out, cnts);
}

// Round 13
// 2160.805 us; speedup vs baseline: 1.9173x; 1.9173x over previous
//
#include <hip/hip_runtime.h>
#include <hip/hip_fp16.h>

#define B_ 512
#define T_ 256
#define H_ 1024
#define G4_ 4096
#define KL_ 20   // k-slices (of 32) resident in LDS
#define KG_ 12   // k-slices from L2
#define PRE_ 2   // L2 slices prefetched across the barrier (32 VGPR)

typedef _Float16 half8 __attribute__((ext_vector_type(8)));
typedef float f32x4 __attribute__((ext_vector_type(4)));

__device__ __forceinline__ float fast_sigmoid(float x) {
    return 1.0f / (1.0f + __expf(-x));
}
__device__ __forceinline__ float fast_tanh(float x) {
    float x2 = fminf(fmaxf(2.0f * x, -30.0f), 30.0f);
    float e = __expf(x2);
    return (e - 1.0f) / (e + 1.0f);
}

// Repack W_hh [4096 x 1024] fp32 -> fp16 MFMA B-fragment order, split into
// W_lds (ki 0..19, per slot 81920 halves, read once at startup) and
// W_l2 (ki 20..31, per j-block 24576 halves; hot set 3 MB/XCD — proven
// non-thrashing in r5-r9; r12's 3.5 MB overflowed L2 and thrashed to HBM).
__global__ void pack_w(const float* __restrict__ Whh,
                       _Float16* __restrict__ Wlds, _Float16* __restrict__ Wl2) {
    int idx = blockIdx.x * blockDim.x + threadIdx.x;   // over 4096*1024
    int gc = idx >> 10, k = idx & 1023;
    int nt = gc >> 10, u = gc & 1023;
    int jb = u >> 4, lk = u & 15;
    int ki = k >> 5, hi = (k >> 3) & 3, e = k & 7;
    int l = hi * 16 + lk;
    _Float16 v = (_Float16)Whh[idx];
    int frag = nt * 512 + l * 8 + e;
    if (ki < KL_) {
        int slot = jb >> 1, wj = jb & 1;
        Wlds[(size_t)slot * 81920 + wj * 40960 + ki * 2048 + frag] = v;
    } else {
        Wl2[(size_t)jb * 24576 + (ki - KL_) * 2048 + frag] = v;
    }
}

__global__ void init_misc(const float* __restrict__ bih, const float* __restrict__ bhh,
                          const float* __restrict__ bout,
                          float* __restrict__ bias, float* __restrict__ out) {
    int idx = blockIdx.x * blockDim.x + threadIdx.x;   // 131072 threads
    if (idx < G4_) bias[idx] = bih[idx] + bhh[idx];
    if (idx < B_ * T_) out[idx] = bout[0];
}

// Persistent kernel, PLAIN launch + startup spin barrier (r12-proven; no
// cooperative launch). 256 WGs x 512 thr, 1 WG/CU (160 KB LDS), 4x2 wave grid
// (r7 geometry, 1787 us baseline). Round-13 change: step REORDERED for L1
// temporal dedup — B-L2 bursts consumed right after the barrier while the 8
// waves are still in lockstep (4 row-waves share B lines, 2 col-waves share A
// lines -> per-CU L1 serves the duplicates), LDS-B slices last where drift is
// free. PRE_ L2 slices are prefetched in the tail; the buffer_inv "memory"
// clobber pins those loads on the pre-barrier side.
__global__ __launch_bounds__(512, 1)
void lstm_persist(const _Float16* __restrict__ Wlds,
                  const _Float16* __restrict__ Wl2,
                  const float* __restrict__ bias,
                  const float* __restrict__ x,
                  const float* __restrict__ Wih,
                  const float* __restrict__ Wout,
                  _Float16* __restrict__ hbuf,        // [8 xcd][2 phase][65536 halves]
                  float* __restrict__ out,
                  unsigned int* __restrict__ cnts) {  // [xcd] slot ctr, [8] startup,
                                                      // [16+xcd*32] barrier, [512+blk] slotmap
    extern __shared__ _Float16 Wl[];   // 81920 halves = 160 KB (full CU LDS)

    const int tid = threadIdx.x;
    unsigned int xcc;
    asm volatile("s_getreg_b32 %0, hwreg(HW_REG_XCC_ID)" : "=s"(xcc));
    const int xcd = (int)(xcc & 7u);
    if (tid == 0) {
        unsigned int s = __hip_atomic_fetch_add(&cnts[xcd], 1u,
                                                __ATOMIC_RELAXED, __HIP_MEMORY_SCOPE_AGENT);
        __hip_atomic_store(&cnts[512 + blockIdx.x], s,
                           __ATOMIC_RELAXED, __HIP_MEMORY_SCOPE_AGENT);
        __hip_atomic_fetch_add(&cnts[8], 1u, __ATOMIC_ACQ_REL, __HIP_MEMORY_SCOPE_AGENT);
        while (__hip_atomic_load(&cnts[8], __ATOMIC_ACQUIRE, __HIP_MEMORY_SCOPE_AGENT) < 256u)
            __builtin_amdgcn_s_sleep(2);
    }
    __syncthreads();
    const int slot = (int)__hip_atomic_load(&cnts[512 + blockIdx.x],
                                            __ATOMIC_RELAXED, __HIP_MEMORY_SCOPE_AGENT);
    const int nactive = (int)min(32u, __hip_atomic_load(&cnts[xcd], __ATOMIC_RELAXED,
                                                        __HIP_MEMORY_SCOPE_AGENT));
    if (slot >= 32) return;   // insurance only (1 WG/CU, 32 CUs/XCD)

    const int w = tid >> 6, l = tid & 63;
    const int lk = l & 15, hi = l >> 4;
    const int wr = w >> 1, wj = w & 1;        // 4 row-waves x 2 col-waves
    const int row0 = wr * 16;                 // local row base (0..48)
    const int u = slot * 32 + wj * 16 + lk;   // hidden unit for this lane

    // one-time: this slot's W ki 0..19 -> LDS (10240 half8)
    {
        const half8* src = (const half8*)(Wlds + (size_t)slot * 81920);
        half8* dst = (half8*)Wl;
#pragma unroll
        for (int o = 0; o < 20; ++o) dst[tid + o * 512] = src[tid + o * 512];
    }
    // one-time per-thread constants
    float bz[4], wi4[4];
#pragma unroll
    for (int nt = 0; nt < 4; ++nt) {
        int gc = nt * 1024 + u;
        bz[nt] = bias[gc];
        wi4[nt] = Wih[gc];
    }
    const float wout = Wout[u];
    int rowsl[4], rowsg[4];
#pragma unroll
    for (int r = 0; r < 4; ++r) {
        rowsl[r] = row0 + hi * 4 + r;
        rowsg[r] = xcd * 64 + rowsl[r];
    }
    const int kb = u >> 3, ue = u & 7;
    f32x4 creg = {0.f, 0.f, 0.f, 0.f};
    __syncthreads();

    _Float16* hx = hbuf + (size_t)xcd * 2 * 65536;
    const _Float16* Bg = Wl2 + ((size_t)slot * 2 + wj) * 24576 + l * 8;
    unsigned int* barp = &cnts[16 + xcd * 32];

    // x for t=0 preloaded; later steps prefetch in the tail
    float xv[4];
#pragma unroll
    for (int r = 0; r < 4; ++r) xv[r] = x[rowsg[r] * T_];

    half8 bbp[PRE_ * 4];   // cross-barrier prefetched B slices (ki 20..20+PRE_-1)

    for (int t = 0; t < T_; ++t) {
        // -------- wait phase (h(t-1) from all slots visible) --------
        if (t > 0) {
            if (tid == 0) {
                unsigned int tgt = (unsigned int)nactive * (unsigned int)t;
                while (__hip_atomic_load(barp, __ATOMIC_RELAXED, __HIP_MEMORY_SCOPE_AGENT) < tgt)
                    __builtin_amdgcn_s_sleep(2);
            }
            __syncthreads();
            asm volatile("buffer_inv sc0" ::: "memory");   // drop stale L1 lines
        }

        const int wb = t & 1, rb = wb ^ 1;
        f32x4 acc[4];
#pragma unroll
        for (int nt = 0; nt < 4; ++nt) {
#pragma unroll
            for (int r = 0; r < 4; ++r) acc[nt][r] = bz[nt] + xv[r] * wi4[nt];
        }

        if (t > 0) {
            const _Float16* Ap = hx + rb * 65536 + hi * 512 + (row0 + lk) * 8;

            // (1) prefetched slices first (loads issued pre-barrier, in regs)
#pragma unroll
            for (int kg = 0; kg < PRE_; ++kg) {
                half8 a = *(const half8*)(Ap + (KL_ + kg) * 2048);
#pragma unroll
                for (int nt = 0; nt < 4; ++nt)
                    acc[nt] = __builtin_amdgcn_mfma_f32_16x16x32_f16(a, bbp[kg * 4 + nt], acc[nt], 0, 0, 0);
            }
            // (2) remaining B-L2 slices in bursts while waves are still in
            // lockstep from the barrier -> 4-way row-dup served by L1
            half8 bb[20];
#pragma unroll
            for (int q = 0; q < 20; ++q)
                bb[q] = *(const half8*)(Bg + (PRE_ + (q >> 2)) * 2048 + (q & 3) * 512);
#pragma unroll
            for (int kg = 0; kg < 5; ++kg) {
                half8 a = *(const half8*)(Ap + (KL_ + PRE_ + kg) * 2048);
#pragma unroll
                for (int nt = 0; nt < 4; ++nt)
                    acc[nt] = __builtin_amdgcn_mfma_f32_16x16x32_f16(a, bb[kg * 4 + nt], acc[nt], 0, 0, 0);
            }
#pragma unroll
            for (int q = 0; q < 20; ++q)
                bb[q] = *(const half8*)(Bg + (PRE_ + 5 + (q >> 2)) * 2048 + (q & 3) * 512);
#pragma unroll
            for (int kg = 0; kg < 5; ++kg) {
                half8 a = *(const half8*)(Ap + (KL_ + PRE_ + 5 + kg) * 2048);
#pragma unroll
                for (int nt = 0; nt < 4; ++nt)
                    acc[nt] = __builtin_amdgcn_mfma_f32_16x16x32_f16(a, bb[kg * 4 + nt], acc[nt], 0, 0, 0);
            }
            // (3) LDS-resident slices last (no L2 involvement; drift is free)
#pragma unroll 5
            for (int ki = 0; ki < KL_; ++ki) {
                half8 a = *(const half8*)(Ap + ki * 2048);
                const _Float16* bp = Wl + wj * 40960 + ki * 2048 + l * 8;
#pragma unroll
                for (int nt = 0; nt < 4; ++nt) {
                    half8 b = *(const half8*)(bp + nt * 512);
                    acc[nt] = __builtin_amdgcn_mfma_f32_16x16x32_f16(a, b, acc[nt], 0, 0, 0);
                }
            }
        }

        // elementwise LSTM update; acc[0..3] = i,f,g,o
        _Float16* hn = hx + wb * 65536;
        float p4[4];
#pragma unroll
        for (int r = 0; r < 4; ++r) {
            float iv = fast_sigmoid(acc[0][r]);
            float fv = fast_sigmoid(acc[1][r]);
            float gv = fast_tanh(acc[2][r]);
            float ov = fast_sigmoid(acc[3][r]);
            float cv = fv * creg[r] + iv * gv;
            creg[r] = cv;
            float hv = ov * fast_tanh(cv);
            hn[(kb * 64 + rowsl[r]) * 8 + ue] = (_Float16)hv;
            p4[r] = hv * wout;
        }

        // -------- arrive: syncthreads drains h stores, then signal --------
        if (t < T_ - 1) {
            __syncthreads();   // per-wave s_waitcnt vmcnt(0) precedes s_barrier
            if (tid == 0)
                __hip_atomic_fetch_add(barp, 1u, __ATOMIC_RELAXED, __HIP_MEMORY_SCOPE_AGENT);
        }

        // tail (overlaps tid0's spin in other CUs): out projection, x and
        // B-slice prefetch for t+1. buffer_inv's "memory" clobber keeps the
        // bbp loads on this side of the barrier.
#pragma unroll
        for (int m = 1; m <= 8; m <<= 1) {
#pragma unroll
            for (int r = 0; r < 4; ++r) p4[r] += __shfl_xor(p4[r], m);
        }
        if (lk == 0) {
#pragma unroll
            for (int r = 0; r < 4; ++r)
                atomicAdd(&out[rowsg[r] * T_ + t], p4[r]);
        }
        if (t < T_ - 1) {
#pragma unroll
            for (int r = 0; r < 4; ++r) xv[r] = x[rowsg[r] * T_ + t + 1];
#pragma unroll
            for (int q = 0; q < PRE_ * 4; ++q)
                bbp[q] = *(const half8*)(Bg + (q >> 2) * 2048 + (q & 3) * 512);
        }
    }
}

extern "C" void kernel_launch(void* const* d_in, const int* in_sizes, int n_in,
                              void* d_out, int out_size, void* d_ws, size_t ws_size,
                              hipStream_t stream) {
    const float* x    = (const float*)d_in[0];
    const float* Wih  = (const float*)d_in[1];
    const float* Whh  = (const float*)d_in[2];
    const float* bih  = (const float*)d_in[3];
    const float* bhh  = (const float*)d_in[4];
    const float* Wout = (const float*)d_in[5];
    const float* bout = (const float*)d_in[6];
    float* out = (float*)d_out;

    char* ws = (char*)d_ws;
    _Float16* Wlds = (_Float16*)ws;                        // 5 MB (32 x 160 KB)
    _Float16* Wl2  = (_Float16*)(ws + 5242880);            // 3 MB (64 x 48 KB)
    _Float16* hbuf = (_Float16*)(ws + (8 << 20));          // 2 MB (8 xcd x 2 x 128 KB)
    float* bias    = (float*)(ws + (10 << 20));            // 16 KB
    unsigned int* cnts = (unsigned int*)(ws + (10 << 20) + (64 << 10));  // 4 KB

    hipMemsetAsync(cnts, 0, 4096, stream);
    pack_w<<<(G4_ * H_) / 256, 256, 0, stream>>>(Whh, Wlds, Wl2);
    init_misc<<<512, 256, 0, stream>>>(bih, bhh, bout, bias, out);

    (void)hipFuncSetAttribute((const void*)lstm_persist,
                              hipFuncAttributeMaxDynamicSharedMemorySize, 163840);
    lstm_persist<<<dim3(256), dim3(512), 163840, stream>>>(
        Wlds, Wl2, bias, x, Wih, Wout, hbuf, out, cnts);
}